// Round 13
// baseline (65.690 us; speedup 1.0000x reference)
//
#include <hip/hip_runtime.h>
#include <hip/hip_bf16.h>

typedef __bf16 bf16x8 __attribute__((ext_vector_type(8)));
typedef float f32x16 __attribute__((ext_vector_type(16)));

#define B_N 2048
#define O_N 2048
#define K_TRI 2080
#define K_TOT 2304
#define K_STEPS 36

__device__ __forceinline__ void gld16(const void* g, void* l) {
    __builtin_amdgcn_global_load_lds(
        (const __attribute__((address_space(1))) void*)g,
        (__attribute__((address_space(3))) void*)l,
        16, 0, 0);
}

// ---------------------------------------------------------------------------
// prep A: blocks [0,2048): S rows ROW-MAJOR per o (max parallelism);
//         blocks [2048,2304): P rows directly in TILED layout (8 b-rows each,
//         full 128B-line writes, no LDS out-buffer).
// Column semantics (absmax-proven since R10):
//   [0,2080) tri-pack: S: A_ii / A_ij+A_ji ; P: x_i*x_j
//   [2080,2144) S:c_hi P:x_hi   [2144,2208) S:c_hi P:x_lo
//   [2208,2272) S:c_lo P:x_hi   2272/2273: S:k_hi/k_lo P:1/1   rest 0
// ---------------------------------------------------------------------------
__global__ __launch_bounds__(256) void rbf_prepA(
    const float* __restrict__ inv, const float* __restrict__ means,
    const float* __restrict__ x, __bf16* __restrict__ Srm,
    __bf16* __restrict__ Pt)
{
    __shared__ float s[64 * 65];
    __shared__ float mld[64];
    __shared__ float uw[128];
    __shared__ unsigned short ptab[K_TRI];

    const int t = threadIdx.x;
    {
        int base = 0;
#pragma unroll 1
        for (int i = 0; i < 64; ++i) {
            if (t < 64 - i) ptab[base + t] = (unsigned short)((i << 8) | (i + t));
            base += 64 - i;
        }
    }

    if ((int)blockIdx.x < O_N) {
        const int o = blockIdx.x;
        const float4* src = (const float4*)(inv + (size_t)o * 4096);
#pragma unroll
        for (int k = 0; k < 4; ++k) {
            const int idx = k * 256 + t;
            const float4 v = src[idx];
            const int i = idx >> 4;
            const int j0 = (idx & 15) * 4;
            s[i * 65 + j0 + 0] = v.x * v.x;
            s[i * 65 + j0 + 1] = v.y * v.y;
            s[i * 65 + j0 + 2] = v.z * v.z;
            s[i * 65 + j0 + 3] = v.w * v.w;
        }
        if (t < 64) mld[t] = means[(size_t)t * O_N + o];
        __syncthreads();
        if (t < 64) {                          // u_j = col-dot
            float u = 0.f;
#pragma unroll
            for (int i = 0; i < 64; ++i) u = fmaf(s[i * 65 + t], mld[i], u);
            uw[t] = u;
        } else if (t < 128) {                  // w_j = row-dot
            const int j = t - 64;
            float w = 0.f;
#pragma unroll
            for (int i = 0; i < 64; ++i) w = fmaf(s[j * 65 + i], mld[i], w);
            uw[64 + j] = w;
        }
        __syncthreads();
        __bf16* Srow = Srm + (size_t)o * K_TOT;
#pragma unroll 1
        for (int c = t; c < K_TOT; c += 256) {
            float v;
            if (c < K_TRI) {
                const int ij = ptab[c];
                const int i = ij >> 8, j = ij & 255;
                v = (i == j) ? s[i * 65 + i] : (s[i * 65 + j] + s[j * 65 + i]);
            } else if (c < 2272) {
                const int j = (c - K_TRI) & 63;
                const float cv = -(uw[j] + uw[64 + j]);
                const __bf16 hi = (__bf16)cv;
                v = (c < 2208) ? (float)hi : (cv - (float)hi);
            } else if (c < 2274) {
                float kk = 0.f;
#pragma unroll
                for (int j = 0; j < 64; ++j) kk = fmaf(uw[j], mld[j], kk);
                const __bf16 khi = (__bf16)kk;
                v = (c == 2272) ? (float)khi : (kk - (float)khi);
            } else v = 0.f;
            Srow[c] = (__bf16)v;
        }
    } else {
        const int b0r = ((int)blockIdx.x - O_N) * 8;   // 8 b-rows per block
#pragma unroll
        for (int q = 0; q < 2; ++q) {
            const int idx = q * 256 + t;
            s[(idx >> 6) * 65 + (idx & 63)] =
                x[(size_t)(b0r + (idx >> 6)) * 64 + (idx & 63)];
        }
        __syncthreads();
        // task = (c8, r8): r8 fastest -> 8 threads share one 128B line
#pragma unroll 1
        for (int q = 0; q < 9; ++q) {
            const int task = q * 256 + t;      // 0..2303
            const int c8 = task >> 3, r8 = task & 7;
            const float* xr = &s[r8 * 65];
            unsigned short w8[8];
#pragma unroll
            for (int e = 0; e < 8; ++e) {
                const int c = c8 * 8 + e;
                float v;
                if (c < K_TRI) {
                    const int ij = ptab[c];
                    v = xr[ij >> 8] * xr[ij & 255];
                } else if (c < 2272) {
                    const float xv = xr[(c - K_TRI) & 63];
                    const __bf16 hi = (__bf16)xv;
                    v = (c < 2144) ? (float)hi
                      : (c < 2208) ? (xv - (float)hi) : (float)hi;
                } else if (c < 2274) v = 1.f;
                else v = 0.f;
                w8[e] = __builtin_bit_cast(unsigned short, (__bf16)v);
            }
            *(bf16x8*)(Pt + ((size_t)c8 * 2048 + b0r + r8) * 8) =
                *(const bf16x8*)w8;
        }
    }
}

// ---------------------------------------------------------------------------
// prep B: transpose Srm (row-major) -> St (tiled [chunk][row][16B]).
// grid 128 = 32 rowgroups x 4 colpasses; block: 64 rows x 72 chunks (1152B).
// LDS row stride 1156B (289 words = 1 mod 32) -> conflict-free both phases.
// Reads: per-row contiguous 1152B; writes: per-chunk 64x16B = 1KB contiguous.
// ---------------------------------------------------------------------------
__global__ __launch_bounds__(256, 2) void rbf_prepB(
    const __bf16* __restrict__ Srm, __bf16* __restrict__ St)
{
    __shared__ __align__(16) char ts[64 * 1156];
    const int t = threadIdx.x;
    const int tb = (int)blockIdx.x >> 2;
    const int cp = (int)blockIdx.x & 3;
    const int o0 = tb * 64;

#pragma unroll 1
    for (int q = 0; q < 18; ++q) {             // 18*256 = 4608 = 64*72 exact
        const int idx = q * 256 + t;
        const int r = idx / 72, c = idx % 72;
        const float4 v = *(const float4*)((const char*)Srm
                          + (size_t)(o0 + r) * (K_TOT * 2) + cp * 1152 + c * 16);
        *(float4*)(&ts[r * 1156 + c * 16]) = v;
    }
    __syncthreads();
#pragma unroll 1
    for (int q = 0; q < 18; ++q) {
        const int idx = q * 256 + t;
        const int c = idx >> 6, r = idx & 63;
        const float4 v = *(const float4*)(&ts[r * 1156 + c * 16]);
        *(float4*)((char*)St + ((size_t)(cp * 72 + c) * 2048 + o0 + r) * 16) = v;
    }
}

// ---------------------------------------------------------------------------
// GEMM: C[128b x 64o]/block; grid 512 -> 2 blocks/CU (LDS 72KB), 2 waves/SIMD
// TLP. 4 waves x (64b x 32o), acc 2 x f32x16, 8 MFMA + 12 ds_read_b128/step.
// LDS [ks][row][16B] (0-conflict proven R11); staging contiguous 2KB/gld16
// round (proven R12). 3 buffers, depth-2 prefetch, 2 raw barriers/step with
// counted vmcnt (12/6/0) - loads never drained mid-loop.
// C-layout (32x32): col = lane&31, row = (r&3)+8*(r>>2)+4*(lane>>5).
// ---------------------------------------------------------------------------
__global__ __launch_bounds__(256, 2) void rbf_gemm(
    const __bf16* __restrict__ P, const __bf16* __restrict__ S,
    float* __restrict__ out)
{
    __shared__ __align__(16) char sAB[3][24576];

    const int tid = threadIdx.x;
    const int lane = tid & 63;
    const int w = tid >> 6;
    const int wr = w >> 1, wc = w & 1;
    const int cl = lane & 31;
    const int h = lane >> 5;

    // 512 = 8 XCD x (4 o-pan x 16 b-pan); per-XCD S slice 1.18MB in its L2
    const int wg = (int)blockIdx.x;
    const int xcd = wg & 7;
    const int loc = wg >> 3;                   // 0..63
    const int oBase = (xcd * 4 + (loc & 3)) * 64;
    const int bBase = (loc >> 2) * 128;

    // staging: 6 gld16/thread/step; rounds 0-3 = A(P,128 rows), 4-5 = B(S,64)
    const char* gsrc[6];
    int ldst[6];
#pragma unroll
    for (int r = 0; r < 6; ++r) {
        if (r < 4) {
            const int ks = 2 * r + (tid >> 7);
            const int row = tid & 127;
            ldst[r] = r * 4096 + tid * 16;
            gsrc[r] = (const char*)P + ((size_t)ks * 2048 + bBase + row) * 16;
        } else {
            const int ks = (r - 4) * 4 + (tid >> 6);
            const int row = tid & 63;
            ldst[r] = 16384 + (r - 4) * 4096 + tid * 16;
            gsrc[r] = (const char*)S + ((size_t)ks * 2048 + oBase + row) * 16;
        }
    }

#define RBF_STAGE(ST) do {                                                    \
    const size_t goA_ = (size_t)(ST) * 262144;  /* A: 8 chunks*2048*16 */     \
    const size_t goB_ = (size_t)(ST) * 262144;  /* B: same K-major stride */  \
    char* d_ = &sAB[(ST) % 3][0];                                             \
    _Pragma("unroll")                                                         \
    for (int r_ = 0; r_ < 4; ++r_) gld16(gsrc[r_] + goA_, d_ + ldst[r_]);     \
    _Pragma("unroll")                                                         \
    for (int r_ = 4; r_ < 6; ++r_) gld16(gsrc[r_] + goB_, d_ + ldst[r_]);     \
} while (0)

    RBF_STAGE(0);
    RBF_STAGE(1);

    const f32x16 zz = {0.f,0.f,0.f,0.f,0.f,0.f,0.f,0.f,
                       0.f,0.f,0.f,0.f,0.f,0.f,0.f,0.f};
    f32x16 acc0 = zz, acc1 = zz;

    const int aoff = (wr * 64 + cl) * 16;          // A: + ks*2048 (+512 row+32)
    const int boff = 16384 + (wc * 32 + cl) * 16;  // B: + ks*1024

#pragma unroll 1
    for (int st = 0; st < K_STEPS; ++st) {
        __builtin_amdgcn_s_barrier();      // all waves done with buf[(st+2)%3]
        if (st + 2 < K_STEPS) {
            RBF_STAGE(st + 2);
            asm volatile("s_waitcnt vmcnt(12)" ::: "memory");
        } else if (st + 1 < K_STEPS) {
            asm volatile("s_waitcnt vmcnt(6)" ::: "memory");
        } else {
            asm volatile("s_waitcnt vmcnt(0)" ::: "memory");
        }
        __builtin_amdgcn_s_barrier();      // everyone's step-st loads landed
        __builtin_amdgcn_sched_barrier(0);
        const char* bp = &sAB[st % 3][0];

        __builtin_amdgcn_s_setprio(1);
#pragma unroll
        for (int sl = 0; sl < 4; ++sl) {
            const int ks = sl * 2 + h;
            const bf16x8 a0 = *(const bf16x8*)(bp + ks * 2048 + aoff);
            const bf16x8 a1 = *(const bf16x8*)(bp + ks * 2048 + aoff + 512);
            const bf16x8 b0 = *(const bf16x8*)(bp + ks * 1024 + boff);
            acc0 = __builtin_amdgcn_mfma_f32_32x32x16_bf16(a0, b0, acc0, 0, 0, 0);
            acc1 = __builtin_amdgcn_mfma_f32_32x32x16_bf16(a1, b0, acc1, 0, 0, 0);
        }
        __builtin_amdgcn_s_setprio(0);
    }
#undef RBF_STAGE

#pragma unroll
    for (int r = 0; r < 16; ++r) {
        const int row32 = (r & 3) + 8 * (r >> 2) + 4 * h;
        const int col = oBase + wc * 32 + cl;
        out[(size_t)(bBase + wr * 64 + row32) * O_N + col] =
            exp2f(acc0[r] * -0.72134752044448170368f);
        out[(size_t)(bBase + wr * 64 + 32 + row32) * O_N + col] =
            exp2f(acc1[r] * -0.72134752044448170368f);
    }
}

extern "C" void kernel_launch(void* const* d_in, const int* in_sizes, int n_in,
                              void* d_out, int out_size, void* d_ws, size_t ws_size,
                              hipStream_t stream)
{
    const float* x = (const float*)d_in[0];
    const float* means = (const float*)d_in[1];
    const float* inv = (const float*)d_in[2];
    float* out = (float*)d_out;

    // workspace: St 9.44 MB | Pt 9.44 MB | Srm 9.44 MB
    const size_t SZ = (size_t)O_N * K_TOT * sizeof(__bf16);
    __bf16* St  = (__bf16*)d_ws;
    __bf16* Pt  = (__bf16*)((char*)d_ws + SZ);
    __bf16* Srm = (__bf16*)((char*)d_ws + 2 * SZ);

    rbf_prepA<<<dim3(O_N + 256), dim3(256), 0, stream>>>(inv, means, x, Srm, Pt);
    rbf_prepB<<<dim3(128), dim3(256), 0, stream>>>(Srm, St);
    rbf_gemm<<<dim3(512), dim3(256), 0, stream>>>(Pt, St, out);

    (void)in_sizes; (void)n_in; (void)out_size; (void)ws_size;
}